// Round 3
// baseline (1036.400 us; speedup 1.0000x reference)
//
#include <hip/hip_runtime.h>
#include <math.h>

#define N_  32
#define T_  8192
#define D_  64
#define K_  64
#define CHUNKS 16
#define TOK_PER_BLOCK (T_ / CHUNKS)    // 512
#define TB 64                          // tokens per LDS batch
#define NBATCH (TOK_PER_BLOCK / TB)    // 8
#define STATS_PER_N (K_ + 2 * K_ * D_) // 8256

typedef float v2f __attribute__((ext_vector_type(2)));

// ---------------------------------------------------------------------------
// prep: A[k] = 2 log w_k - 0.5*sum_d(log c + mu^2/c)
//       bg[k][0:64] = mu/c (b row), bg[k][64:128] = -0.5/c (g row)
//       row-contiguous per k so the main kernel's wave-uniform reads become s_loads
// ---------------------------------------------------------------------------
__global__ void prep_kernel(const float* __restrict__ w, const float* __restrict__ mu,
                            const float* __restrict__ cv, float* __restrict__ Ap,
                            float* __restrict__ bg) {
    int tid = threadIdx.x;
    for (int e = tid; e < K_ * D_; e += blockDim.x) {
        int k = e >> 6, d = e & 63;
        float c = cv[e];
        bg[k * 128 + d]      = mu[e] / c;
        bg[k * 128 + 64 + d] = -0.5f / c;
    }
    if (tid < K_) {
        int k = tid;
        float acc = 0.f;
        for (int d = 0; d < D_; ++d) {
            int idx = k * D_ + d;
            float c = cv[idx], m = mu[idx];
            acc += logf(c) + m * m / c;
        }
        Ap[k] = 2.f * logf(w[k]) - 0.5f * acc;
    }
}

// ---------------------------------------------------------------------------
// main: grid (16, 32) = 512 blocks (2/CU), block 256 (4 waves).
// Per 64-token batch:
//   stage:   coalesced global->LDS of x and x^2, float4 XOR-swizzled layout
//   Phase A: lane=token. wave w computes k in [16w,16w+16): per k two pk-fma
//            chains over d with b/g rows from wave-uniform s_loads. Cross-wave
//            softmax via tiny LDS reduction. p written back swizzled.
//   Phase B: thread (ki,dj) owns 4k x 4d tile; b128 reads of p/x/x^2 (t uniform
//            -> broadcast-heavy, conflict-free), pk-fma rank-1 updates.
// ---------------------------------------------------------------------------
__launch_bounds__(256, 2)
__global__ void main_kernel(const float* __restrict__ x, const float* __restrict__ Ap,
                            const float* __restrict__ bg, float* __restrict__ stats) {
    __shared__ float4 X4[TB * 16];   // 16 KB  x,  swizzled float4 rows
    __shared__ float4 Q4[TB * 16];   // 16 KB  x^2
    __shared__ float4 P4[TB * 16];   // 16 KB  p
    __shared__ float  redm[TB * 4];  // per-wave partial max
    __shared__ float  reds[TB * 4];  // per-wave partial expsum

    const int tid  = threadIdx.x;
    const int lane = tid & 63;
    const int wv   = __builtin_amdgcn_readfirstlane(tid >> 6);  // uniform 0..3
    const int c0   = lane & 15;
    const int chunk = blockIdx.x;
    const int n     = blockIdx.y;

    const float* bgw = bg + wv * 16 * 128;   // this wave's 16 k-rows (uniform)

    // Phase-B tile ownership
    const int ki = tid >> 4;   // 0..15 -> k = 4*ki + a
    const int dj = tid & 15;   // 0..15 -> d = 4*dj + b
    v2f a1[4][2], a2[4][2];
#pragma unroll
    for (int a = 0; a < 4; ++a)
#pragma unroll
        for (int g = 0; g < 2; ++g) { a1[a][g] = (v2f)(0.f); a2[a][g] = (v2f)(0.f); }
    float S0loc[16];
#pragma unroll
    for (int j = 0; j < 16; ++j) S0loc[j] = 0.f;

    const size_t xbase = ((size_t)n * T_ + (size_t)chunk * TOK_PER_BLOCK) * (size_t)D_;

#pragma unroll 1
    for (int batch = 0; batch < NBATCH; ++batch) {
        // ---------------- stage ----------------
        {
            const float* xb = x + xbase + (size_t)batch * TB * D_;
#pragma unroll
            for (int i = 0; i < 4; ++i) {
                const int f = i * 256 + tid;        // float4 id 0..1023
                const int t = f >> 4, c = f & 15;
                const float4 v = *(const float4*)(xb + t * 64 + c * 4);
                const int s = c ^ (t & 15);
                X4[t * 16 + s] = v;
                Q4[t * 16 + s] = make_float4(v.x * v.x, v.y * v.y, v.z * v.z, v.w * v.w);
            }
        }
        __syncthreads();

        // ---------------- Phase A ----------------
        float p[16];   // logits -> e -> p for this wave's 16 k's
        {
            v2f acc1[16], acc2[16];
#pragma unroll
            for (int j = 0; j < 16; ++j) {
                acc1[j] = (v2f){Ap[wv * 16 + j], 0.f};   // fold A into acc1
                acc2[j] = (v2f)(0.f);
            }
#pragma unroll
            for (int h = 0; h < 2; ++h) {   // d-chunks of 32
                v2f xv2[16], qv2[16];
#pragma unroll
                for (int j = 0; j < 8; ++j) {
                    const int s = (h * 8 + j) ^ c0;
                    const float4 v = X4[lane * 16 + s];
                    const float4 q = Q4[lane * 16 + s];
                    xv2[2 * j]     = (v2f){v.x, v.y};
                    xv2[2 * j + 1] = (v2f){v.z, v.w};
                    qv2[2 * j]     = (v2f){q.x, q.y};
                    qv2[2 * j + 1] = (v2f){q.z, q.w};
                }
#pragma unroll
                for (int j = 0; j < 16; ++j) {
                    const v2f* rb = (const v2f*)(bgw + j * 128 + h * 32);       // b chunk (uniform)
                    const v2f* rg = (const v2f*)(bgw + j * 128 + 64 + h * 32);  // g chunk (uniform)
#pragma unroll
                    for (int dd = 0; dd < 16; ++dd) {
                        acc1[j] = __builtin_elementwise_fma(xv2[dd], rb[dd], acc1[j]);
                        acc2[j] = __builtin_elementwise_fma(qv2[dd], rg[dd], acc2[j]);
                    }
                }
            }
            // combine + per-lane max over this wave's 16 k's
            float m = -INFINITY;
#pragma unroll
            for (int j = 0; j < 16; ++j) {
                p[j] = (acc1[j].x + acc1[j].y) + (acc2[j].x + acc2[j].y);  // logit
                m = fmaxf(m, p[j]);
            }
            redm[lane * 4 + wv] = m;
        }
        __syncthreads();
        {
            const float4 m4 = *(const float4*)&redm[lane * 4];
            const float m = fmaxf(fmaxf(m4.x, m4.y), fmaxf(m4.z, m4.w));
            float s = 0.f;
#pragma unroll
            for (int j = 0; j < 16; ++j) {
                p[j] = __expf(p[j] - m);
                s += p[j];
            }
            reds[lane * 4 + wv] = s;
        }
        __syncthreads();
        {
            const float4 s4 = *(const float4*)&reds[lane * 4];
            const float rs = 1.f / ((s4.x + s4.y) + (s4.z + s4.w));
#pragma unroll
            for (int j = 0; j < 16; ++j) {
                p[j] *= rs;
                S0loc[j] += p[j];
            }
            // write p back, swizzled float4 groups g = 4*wv + uu
#pragma unroll
            for (int uu = 0; uu < 4; ++uu) {
                const int g = 4 * wv + uu;
                P4[lane * 16 + (g ^ c0)] =
                    make_float4(p[4 * uu], p[4 * uu + 1], p[4 * uu + 2], p[4 * uu + 3]);
            }
        }
        __syncthreads();

        // ---------------- Phase B ----------------
#pragma unroll
        for (int c = 0; c < 16; ++c) {
            const int sp = (ki ^ c);
            const int sx = (dj ^ c);
#pragma unroll
            for (int r = 0; r < 4; ++r) {
                const int t = r * 16 + c;
                const float4 pv = P4[t * 16 + sp];
                const float4 xv = X4[t * 16 + sx];
                const float4 qv = Q4[t * 16 + sx];
                const v2f xlo = (v2f){xv.x, xv.y}, xhi = (v2f){xv.z, xv.w};
                const v2f qlo = (v2f){qv.x, qv.y}, qhi = (v2f){qv.z, qv.w};
                const float pa[4] = {pv.x, pv.y, pv.z, pv.w};
#pragma unroll
                for (int a = 0; a < 4; ++a) {
                    const v2f pb = (v2f)(pa[a]);
                    a1[a][0] = __builtin_elementwise_fma(pb, xlo, a1[a][0]);
                    a1[a][1] = __builtin_elementwise_fma(pb, xhi, a1[a][1]);
                    a2[a][0] = __builtin_elementwise_fma(pb, qlo, a2[a][0]);
                    a2[a][1] = __builtin_elementwise_fma(pb, qhi, a2[a][1]);
                }
            }
        }
        __syncthreads();
    }

    // -------- flush partials --------
    float* sb = stats + (size_t)n * STATS_PER_N;
#pragma unroll
    for (int j = 0; j < 16; ++j) {
        float v = S0loc[j];
#pragma unroll
        for (int off = 32; off > 0; off >>= 1) v += __shfl_xor(v, off, 64);
        if (lane == 0) atomicAdd(&sb[wv * 16 + j], v);
    }
#pragma unroll
    for (int a = 0; a < 4; ++a)
#pragma unroll
        for (int g = 0; g < 2; ++g) {
            const int idx = (ki * 4 + a) * 64 + dj * 4 + 2 * g;
            atomicAdd(&sb[64 + idx],            a1[a][g].x);
            atomicAdd(&sb[64 + idx + 1],        a1[a][g].y);
            atomicAdd(&sb[64 + 4096 + idx],     a2[a][g].x);
            atomicAdd(&sb[64 + 4096 + idx + 1], a2[a][g].y);
        }
}

// ---------------------------------------------------------------------------
// finalize: v0/v1/v2, signed sqrt, L2 normalize per n. grid = N, block = 256.
// ---------------------------------------------------------------------------
__global__ void fin_kernel(const float* __restrict__ w, const float* __restrict__ mu,
                           const float* __restrict__ cv, const float* __restrict__ stats,
                           float* __restrict__ out) {
    __shared__ float us[STATS_PER_N];   // 33 KB
    __shared__ float red[4];
    const int n   = blockIdx.x;
    const int tid = threadIdx.x;
    const float* sb = stats + (size_t)n * STATS_PER_N;

    float ss = 0.f;
    for (int e = tid; e < STATS_PER_N; e += 256) {
        const int k = e / 129;
        const int r = e - k * 129;
        const float wv  = w[k];
        const float s0v = sb[k];
        float v;
        if (r == 0) {
            v = (s0v - (float)T_ * wv) * rsqrtf(wv);
        } else if (r < 65) {
            const int idx = k * 64 + (r - 1);
            v = (sb[64 + idx] - mu[idx] * s0v) * rsqrtf(wv * cv[idx]);
        } else {
            const int idx = k * 64 + (r - 65);
            const float m_ = mu[idx], c_ = cv[idx];
            const float s1v = sb[64 + idx], s2v = sb[64 + 4096 + idx];
            v = (s2v - 2.f * m_ * s1v + (m_ * m_ - c_) * s0v) * (rsqrtf(2.f * wv) / c_);
        }
        const float u = (v >= 0.f) ? sqrtf(v) : -sqrtf(-v);
        us[e] = u;
        ss = fmaf(u, u, ss);
    }
#pragma unroll
    for (int off = 32; off > 0; off >>= 1) ss += __shfl_xor(ss, off, 64);
    if ((tid & 63) == 0) red[tid >> 6] = ss;
    __syncthreads();
    const float tot = red[0] + red[1] + red[2] + red[3];
    const float rn = rsqrtf(tot);
    for (int e = tid; e < STATS_PER_N; e += 256)
        out[(size_t)n * STATS_PER_N + e] = us[e] * rn;
}

// ---------------------------------------------------------------------------
extern "C" void kernel_launch(void* const* d_in, const int* in_sizes, int n_in,
                              void* d_out, int out_size, void* d_ws, size_t ws_size,
                              hipStream_t stream) {
    const float* x  = (const float*)d_in[0];
    const float* w  = (const float*)d_in[1];
    const float* mu = (const float*)d_in[2];
    const float* cv = (const float*)d_in[3];
    float* out = (float*)d_out;

    // workspace layout (floats): stats[N*8256] | A[64] | bg[64*128]
    float* stats = (float*)d_ws;
    float* Ap = stats + (size_t)N_ * STATS_PER_N;
    float* bg = Ap + K_;

    hipMemsetAsync(stats, 0, (size_t)N_ * STATS_PER_N * sizeof(float), stream);

    prep_kernel<<<1, 256, 0, stream>>>(w, mu, cv, Ap, bg);
    main_kernel<<<dim3(CHUNKS, N_), 256, 0, stream>>>(x, Ap, bg, stats);
    fin_kernel<<<N_, 256, 0, stream>>>(w, mu, cv, stats, out);
}

// Round 4
// 286.733 us; speedup vs baseline: 3.6145x; 3.6145x over previous
//
#include <hip/hip_runtime.h>
#include <math.h>

#define N_  32
#define T_  8192
#define D_  64
#define K_  64
#define CHUNKS 16
#define TOK_PER_BLOCK (T_ / CHUNKS)    // 512
#define TB 64                          // tokens per batch
#define NBATCH (TOK_PER_BLOCK / TB)    // 8
#define STATS_PER_N (K_ + 2 * K_ * D_) // 8256
#define LDS_STRIDE 72                  // f16 elems per row (64 + 8 pad)

typedef _Float16 half_t;
typedef __attribute__((ext_vector_type(8)))  _Float16 v8h;
typedef __attribute__((ext_vector_type(2)))  _Float16 v2h;
typedef __attribute__((ext_vector_type(4)))  float    v4f;
typedef __attribute__((ext_vector_type(16))) float    v16f;

// ---------------------------------------------------------------------------
// prep: Ap[k] = 2 log w - 0.5*sum_d(log c + mu^2/c)
//       WH = f16 weight matrix W[kc][f] (f<64: mu/c ; f>=64: -0.5/c), packed in
//       MFMA A-fragment order: element ((tile*4+s)*64 + lane)*8 + j holds
//       W[16*tile + (lane&15)][32*s + 8*(lane>>4) + j]
// ---------------------------------------------------------------------------
__global__ void prep_kernel(const float* __restrict__ w, const float* __restrict__ mu,
                            const float* __restrict__ cv, float* __restrict__ Ap,
                            half_t* __restrict__ WH) {
    const int tid = threadIdx.x;
    for (int e = tid; e < K_ * 128; e += 256) {
        const int j = e & 7, l = (e >> 3) & 63, fs = e >> 9;
        const int tile = fs >> 2, s = fs & 3;
        const int kc = 16 * tile + (l & 15);
        const int f  = 32 * s + 8 * (l >> 4) + j;
        float val;
        if (f < 64) val = mu[kc * 64 + f] / cv[kc * 64 + f];
        else        val = -0.5f / cv[kc * 64 + (f - 64)];
        WH[e] = (half_t)val;
    }
    if (tid < K_) {
        const int k = tid;
        float acc = 0.f;
        for (int d = 0; d < D_; ++d) {
            const int idx = k * D_ + d;
            const float c = cv[idx], m = mu[idx];
            acc += logf(c) + m * m / c;
        }
        Ap[k] = 2.f * logf(w[k]) - 0.5f * acc;
    }
}

// ---------------------------------------------------------------------------
// main: grid (16, 32) = 512 blocks, block 256 (4 waves).
// Phase A: mfma 16x16x32_f16, A = resident weight frags (64 VGPR), B = 16
//          tokens/wave from LDS (b128). D[kc][tok]: col=tok, 16 kc rows/lane.
//          Softmax in-register (shfl_xor 16,32). p -> LDS (packed b32 pairs).
// Phase B: mfma 32x32x16_f16. wave w: matrix sig=w>>1 (s1|s2), d-half w&1.
//          A = P[t][kc] gathers, B = X|Q[t][d] gathers (ds_read_u16, 2-way ok).
//          Accumulate all 512 tokens in 32 AGPRs; one atomic flush per block.
// ---------------------------------------------------------------------------
__launch_bounds__(256, 2)
__global__ void main_kernel(const float* __restrict__ x, const float* __restrict__ Ap,
                            const half_t* __restrict__ WH, float* __restrict__ stats) {
    __shared__ half_t Xs[TB][LDS_STRIDE];   // 9.2 KB
    __shared__ half_t Qs[TB][LDS_STRIDE];   // 9.2 KB
    __shared__ half_t Ps[TB][LDS_STRIDE];   // 9.2 KB

    const int tid  = threadIdx.x;
    const int lane = tid & 63;
    const int wv   = tid >> 6;
    const int chunk = blockIdx.x;
    const int n     = blockIdx.y;
    const int q     = lane >> 4;     // quad within wave (Phase A)

    // resident weight A-frags: Wf[tile*4+step]
    v8h Wf[16];
#pragma unroll
    for (int t = 0; t < 4; ++t)
#pragma unroll
        for (int s = 0; s < 4; ++s)
            Wf[t * 4 + s] = *(const v8h*)(WH + (size_t)((t * 4 + s) * 64 + lane) * 8);

    // per-lane Ap for its 16 kc's: kc = 16*tile + 4*q + r
    float apv[16];
#pragma unroll
    for (int t = 0; t < 4; ++t)
#pragma unroll
        for (int r = 0; r < 4; ++r) apv[t * 4 + r] = Ap[16 * t + 4 * q + r];

    float S0loc[16];
#pragma unroll
    for (int j = 0; j < 16; ++j) S0loc[j] = 0.f;

    const int sig = wv >> 1;   // 0: s1 (B from Xs), 1: s2 (B from Qs)
    const int dh  = wv & 1;    // d-half
    v16f accB[2];
#pragma unroll
    for (int m = 0; m < 2; ++m)
#pragma unroll
        for (int r = 0; r < 16; ++r) accB[m][r] = 0.f;

    const size_t xbase = ((size_t)n * T_ + (size_t)chunk * TOK_PER_BLOCK) * (size_t)D_;

#pragma unroll 1
    for (int batch = 0; batch < NBATCH; ++batch) {
        // ---------------- stage ----------------
        {
            const float* xb = x + xbase + (size_t)batch * TB * D_;
#pragma unroll
            for (int i = 0; i < 2; ++i) {
                const int g = i * 256 + tid;         // unit 0..511 (8 f16 each)
                const int t = g >> 3, uu = g & 7;
                const float4 v0 = *(const float4*)(xb + t * 64 + uu * 8);
                const float4 v1 = *(const float4*)(xb + t * 64 + uu * 8 + 4);
                v8h xh, qh;
                xh[0] = (half_t)v0.x; xh[1] = (half_t)v0.y; xh[2] = (half_t)v0.z; xh[3] = (half_t)v0.w;
                xh[4] = (half_t)v1.x; xh[5] = (half_t)v1.y; xh[6] = (half_t)v1.z; xh[7] = (half_t)v1.w;
                qh[0] = (half_t)(v0.x * v0.x); qh[1] = (half_t)(v0.y * v0.y);
                qh[2] = (half_t)(v0.z * v0.z); qh[3] = (half_t)(v0.w * v0.w);
                qh[4] = (half_t)(v1.x * v1.x); qh[5] = (half_t)(v1.y * v1.y);
                qh[6] = (half_t)(v1.z * v1.z); qh[7] = (half_t)(v1.w * v1.w);
                *(v8h*)&Xs[t][uu * 8] = xh;
                *(v8h*)&Qs[t][uu * 8] = qh;
            }
        }
        __syncthreads();

        // ---------------- Phase A ----------------
        {
            const int tok = 16 * wv + (lane & 15);   // this lane's token (local)
            v4f acc[4];
#pragma unroll
            for (int t = 0; t < 4; ++t) acc[t] = (v4f)(0.f);
#pragma unroll
            for (int s = 0; s < 4; ++s) {
                const half_t* src = (s < 2) ? &Xs[0][0] : &Qs[0][0];
                const int d0 = (s & 1) * 32 + q * 8;
                const v8h bf = *(const v8h*)(src + tok * LDS_STRIDE + d0);
#pragma unroll
                for (int t = 0; t < 4; ++t)
                    acc[t] = __builtin_amdgcn_mfma_f32_16x16x32_f16(Wf[t * 4 + s], bf, acc[t], 0, 0, 0);
            }
            float pv[16];
            float m = -1e30f;
#pragma unroll
            for (int t = 0; t < 4; ++t)
#pragma unroll
                for (int r = 0; r < 4; ++r) {
                    const float lg = acc[t][r] + apv[t * 4 + r];
                    pv[t * 4 + r] = lg;
                    m = fmaxf(m, lg);
                }
            m = fmaxf(m, __shfl_xor(m, 16, 64));
            m = fmaxf(m, __shfl_xor(m, 32, 64));
            float ssum = 0.f;
#pragma unroll
            for (int j = 0; j < 16; ++j) { pv[j] = __expf(pv[j] - m); ssum += pv[j]; }
            ssum += __shfl_xor(ssum, 16, 64);
            ssum += __shfl_xor(ssum, 32, 64);
            const float rs = 1.f / ssum;
#pragma unroll
            for (int j = 0; j < 16; ++j) { pv[j] *= rs; S0loc[j] += pv[j]; }
            // write p: kc pairs (4B-aligned packed writes)
#pragma unroll
            for (int t = 0; t < 4; ++t)
#pragma unroll
                for (int rr = 0; rr < 2; ++rr) {
                    v2h pr;
                    pr[0] = (half_t)pv[t * 4 + rr * 2];
                    pr[1] = (half_t)pv[t * 4 + rr * 2 + 1];
                    *(v2h*)&Ps[tok][16 * t + 4 * q + rr * 2] = pr;
                }
        }
        __syncthreads();

        // ---------------- Phase B ----------------
        {
            const half_t* Bsrc = (sig == 0) ? &Xs[0][0] : &Qs[0][0];
            const int dloc = lane & 31;
            const int d = 32 * dh + dloc;
            const int th = 8 * (lane >> 5);
#pragma unroll
            for (int st = 0; st < 4; ++st) {
                const int tB = 16 * st + th;
                v8h bf, a0, a1;
#pragma unroll
                for (int j = 0; j < 8; ++j) {
                    bf[j] = Bsrc[(tB + j) * LDS_STRIDE + d];
                    a0[j] = Ps[tB + j][dloc];
                    a1[j] = Ps[tB + j][32 + dloc];
                }
                accB[0] = __builtin_amdgcn_mfma_f32_32x32x16_f16(a0, bf, accB[0], 0, 0, 0);
                accB[1] = __builtin_amdgcn_mfma_f32_32x32x16_f16(a1, bf, accB[1], 0, 0, 0);
            }
        }
        __syncthreads();
    }

    // -------- flush partials --------
    float* sb = stats + (size_t)n * STATS_PER_N;
    // s0: reduce over the 16 token-lanes sharing q
#pragma unroll
    for (int j = 0; j < 16; ++j) {
        float v = S0loc[j];
        v += __shfl_xor(v, 1, 64);
        v += __shfl_xor(v, 2, 64);
        v += __shfl_xor(v, 4, 64);
        v += __shfl_xor(v, 8, 64);
        S0loc[j] = v;
    }
    if ((lane & 15) == 0) {
#pragma unroll
        for (int t = 0; t < 4; ++t)
#pragma unroll
            for (int r = 0; r < 4; ++r)
                atomicAdd(&sb[16 * t + 4 * q + r], S0loc[t * 4 + r]);
    }
    // s1/s2: C/D layout 32x32: col = lane&31 (=d_local), row = (reg&3)+8*(reg>>2)+4*(lane>>5)
    {
        const int d = 32 * dh + (lane & 31);
        float* dst = sb + 64 + sig * 4096;
#pragma unroll
        for (int mt = 0; mt < 2; ++mt)
#pragma unroll
            for (int r = 0; r < 16; ++r) {
                const int kc = 32 * mt + (r & 3) + 8 * (r >> 2) + 4 * (lane >> 5);
                atomicAdd(&dst[kc * 64 + d], accB[mt][r]);
            }
    }
}

// ---------------------------------------------------------------------------
// finalize: v0/v1/v2, signed sqrt, L2 normalize per n. grid = N, block = 256.
// ---------------------------------------------------------------------------
__global__ void fin_kernel(const float* __restrict__ w, const float* __restrict__ mu,
                           const float* __restrict__ cv, const float* __restrict__ stats,
                           float* __restrict__ out) {
    __shared__ float us[STATS_PER_N];   // 33 KB
    __shared__ float red[4];
    const int n   = blockIdx.x;
    const int tid = threadIdx.x;
    const float* sb = stats + (size_t)n * STATS_PER_N;

    float ss = 0.f;
    for (int e = tid; e < STATS_PER_N; e += 256) {
        const int k = e / 129;
        const int r = e - k * 129;
        const float wv  = w[k];
        const float s0v = sb[k];
        float v;
        if (r == 0) {
            v = (s0v - (float)T_ * wv) * rsqrtf(wv);
        } else if (r < 65) {
            const int idx = k * 64 + (r - 1);
            v = (sb[64 + idx] - mu[idx] * s0v) * rsqrtf(wv * cv[idx]);
        } else {
            const int idx = k * 64 + (r - 65);
            const float m_ = mu[idx], c_ = cv[idx];
            const float s1v = sb[64 + idx], s2v = sb[64 + 4096 + idx];
            v = (s2v - 2.f * m_ * s1v + (m_ * m_ - c_) * s0v) * (rsqrtf(2.f * wv) / c_);
        }
        const float u = (v >= 0.f) ? sqrtf(v) : -sqrtf(-v);
        us[e] = u;
        ss = fmaf(u, u, ss);
    }
#pragma unroll
    for (int off = 32; off > 0; off >>= 1) ss += __shfl_xor(ss, off, 64);
    if ((tid & 63) == 0) red[tid >> 6] = ss;
    __syncthreads();
    const float tot = red[0] + red[1] + red[2] + red[3];
    const float rn = rsqrtf(tot);
    for (int e = tid; e < STATS_PER_N; e += 256)
        out[(size_t)n * STATS_PER_N + e] = us[e] * rn;
}

// ---------------------------------------------------------------------------
extern "C" void kernel_launch(void* const* d_in, const int* in_sizes, int n_in,
                              void* d_out, int out_size, void* d_ws, size_t ws_size,
                              hipStream_t stream) {
    const float* x  = (const float*)d_in[0];
    const float* w  = (const float*)d_in[1];
    const float* mu = (const float*)d_in[2];
    const float* cv = (const float*)d_in[3];
    float* out = (float*)d_out;

    // ws layout: stats[N*8256] f32 | Ap[64] f32 | WH[64*128] f16
    float* stats = (float*)d_ws;
    float* Ap = stats + (size_t)N_ * STATS_PER_N;
    half_t* WH = (half_t*)(Ap + K_);

    hipMemsetAsync(stats, 0, (size_t)N_ * STATS_PER_N * sizeof(float), stream);

    prep_kernel<<<1, 256, 0, stream>>>(w, mu, cv, Ap, WH);
    main_kernel<<<dim3(CHUNKS, N_), 256, 0, stream>>>(x, Ap, WH, stats);
    fin_kernel<<<N_, 256, 0, stream>>>(w, mu, cv, stats, out);
}